// Round 7
// baseline (629.855 us; speedup 1.0000x reference)
//
#include <hip/hip_runtime.h>

#define LEAKY(v) ((v) > 0.f ? (v) : 0.01f * (v))

typedef __attribute__((ext_vector_type(8))) short bf16x8;
typedef __attribute__((ext_vector_type(4))) short bf16x4;
typedef __attribute__((ext_vector_type(4))) float floatx4;

__device__ inline unsigned short f2bf(float f) {
  unsigned u = __float_as_uint(f);
  unsigned r = u + 0x7FFFu + ((u >> 16) & 1u);
  return (unsigned short)(r >> 16);
}

__device__ inline bf16x8 ld_frag8(const unsigned short* p) {
  bf16x4 lo = *(const bf16x4*)p;
  bf16x4 hi = *(const bf16x4*)(p + 4);
  return __builtin_shufflevector(lo, hi, 0, 1, 2, 3, 4, 5, 6, 7);
}

// ---------------- mega-prep: style(14) + W2(9) + wprep(6) in ONE dispatch ----------------
struct StyleDesc { const float* sw; const float* sb; int row; int cin; };
struct StyleArgs { StyleDesc d[14]; };
struct W2D { const float* w; int cinLog; int coutLog; int start; int w2off; };
struct W2Args { W2D d[9]; int total4; };
struct WPD { const float* src; unsigned short* dst; int cin; int cout; int start; };
struct WPArgs { WPD d[6]; int total; };

__device__ void style_body(int bid, const float* __restrict__ lat, const StyleArgs& A,
                           float* __restrict__ S)
{
  int chunk = bid & 1, b = (bid >> 1) & 1, sid = bid >> 2;
  StyleDesc d = A.d[sid];
  int ci = chunk * 256 + threadIdx.x;
  if (ci >= d.cin) return;
  const float* l = lat + (size_t)b * (10 * 512) + d.row * 512;
  float a0 = 0.f, a1 = 0.f, a2 = 0.f, a3 = 0.f, a4 = 0.f, a5 = 0.f, a6 = 0.f, a7 = 0.f;
  const float* wp = d.sw + ci;
  size_t st = d.cin;
  for (int k = 0; k < 512; k += 8) {
    a0 += l[k] * wp[0];
    a1 += l[k + 1] * wp[st];
    a2 += l[k + 2] * wp[2 * st];
    a3 += l[k + 3] * wp[3 * st];
    a4 += l[k + 4] * wp[4 * st];
    a5 += l[k + 5] * wp[5 * st];
    a6 += l[k + 6] * wp[6 * st];
    a7 += l[k + 7] * wp[7 * st];
    wp += 8 * st;
  }
  S[sid * 1024 + b * 512 + ci] = d.sb[ci] + ((a0 + a1) + (a2 + a3)) + ((a4 + a5) + (a6 + a7));
}

__device__ void w2_body(int idx, const W2Args& A, float* __restrict__ W2)
{
  if (idx >= A.total4) return;
  int c = 0;
  while (c < 8 && idx >= A.d[c + 1].start) c++;
  W2D d = A.d[c];
  int rel = idx - d.start;
  int co4Log = d.coutLog - 2;
  int ci = rel >> co4Log;
  int co = (rel & ((1 << co4Log) - 1)) << 2;
  size_t ktStride = (size_t)(1 << d.cinLog) << d.coutLog;
  const float* p = d.w + ((size_t)ci << d.coutLog) + co;
  float4 acc = {0.f, 0.f, 0.f, 0.f};
#pragma unroll
  for (int kt = 0; kt < 9; kt++) {
    float4 v = *(const float4*)(p + kt * ktStride);
    acc.x += v.x * v.x; acc.y += v.y * v.y; acc.z += v.z * v.z; acc.w += v.w * v.w;
  }
  *(float4*)(W2 + d.w2off + ((size_t)ci << d.coutLog) + co) = acc;
}

__device__ void wprep_body(int chunk, const WPArgs& A)
{
  if (chunk >= A.total) return;
  int c = 0;
  while (c < 5 && chunk >= A.d[c + 1].start) c++;
  WPD d = A.d[c];
  int rel = chunk - d.start;
  int cpc = d.cin * 9 / 8;
  int co = rel / cpc;
  int k0 = (rel - co * cpc) * 8;
  int cig = k0 / 288;
  int r = k0 - cig * 288;
  int kt = r >> 5;
  int cibase = cig * 32 + (r & 31);
  const float* sp = d.src + (size_t)(kt * d.cin + cibase) * d.cout + co;
  size_t st = d.cout;
  unsigned r0 = f2bf(sp[0]) | ((unsigned)f2bf(sp[st]) << 16);
  unsigned r1 = f2bf(sp[2 * st]) | ((unsigned)f2bf(sp[3 * st]) << 16);
  unsigned r2 = f2bf(sp[4 * st]) | ((unsigned)f2bf(sp[5 * st]) << 16);
  unsigned r3 = f2bf(sp[6 * st]) | ((unsigned)f2bf(sp[7 * st]) << 16);
  uint4 v = {r0, r1, r2, r3};
  *(uint4*)(d.dst + (size_t)co * (d.cin * 9) + k0) = v;
}

__global__ __launch_bounds__(256) void prep_all_kernel(
    const float* __restrict__ lat, StyleArgs SA, W2Args WA, WPArgs PA,
    float* __restrict__ S, float* __restrict__ W2, int styleBlocks, int w2Blocks)
{
  int bid = blockIdx.x;
  if (bid < styleBlocks) { style_body(bid, lat, SA, S); return; }
  bid -= styleBlocks;
  if (bid < w2Blocks) { w2_body(bid * 256 + threadIdx.x, WA, W2); return; }
  bid -= w2Blocks;
  wprep_body(bid * 256 + threadIdx.x, PA);
}

// ---------------- demod2 ----------------
struct D2D { int w2off; int sid; int did; int cin; int cout; int start; };
struct D2Args { D2D d[9]; };

__global__ __launch_bounds__(256) void demod2_all_kernel(
    D2Args A, const float* __restrict__ W2, const float* __restrict__ S,
    float* __restrict__ Dout)
{
  __shared__ float red[256];
  int bid = blockIdx.x;
  int c = 0;
  while (c < 8 && bid >= A.d[c + 1].start) c++;
  D2D d = A.d[c];
  int rel = bid - d.start;
  int chunksPerB = d.cout >> 6;
  int b = rel / chunksPerB;
  int coc = rel - b * chunksPerB;
  int co = coc * 64 + (threadIdx.x & 63);
  int slice = threadIdx.x >> 6;
  const float* sv = S + d.sid * 1024 + b * 512;
  const float* wp = W2 + d.w2off + co;
  float a0 = 0.f, a1 = 0.f, a2 = 0.f, a3 = 0.f, a4 = 0.f, a5 = 0.f, a6 = 0.f, a7 = 0.f;
  for (int r = slice; r < d.cin; r += 32) {
    float s0 = sv[r];          a0 += s0 * s0 * wp[(size_t)r * d.cout];
    float s1 = sv[r + 4];      a1 += s1 * s1 * wp[(size_t)(r + 4) * d.cout];
    float s2 = sv[r + 8];      a2 += s2 * s2 * wp[(size_t)(r + 8) * d.cout];
    float s3 = sv[r + 12];     a3 += s3 * s3 * wp[(size_t)(r + 12) * d.cout];
    float s4 = sv[r + 16];     a4 += s4 * s4 * wp[(size_t)(r + 16) * d.cout];
    float s5 = sv[r + 20];     a5 += s5 * s5 * wp[(size_t)(r + 20) * d.cout];
    float s6 = sv[r + 24];     a6 += s6 * s6 * wp[(size_t)(r + 24) * d.cout];
    float s7 = sv[r + 28];     a7 += s7 * s7 * wp[(size_t)(r + 28) * d.cout];
  }
  red[threadIdx.x] = ((a0 + a1) + (a2 + a3)) + ((a4 + a5) + (a6 + a7));
  __syncthreads();
  if (threadIdx.x < 64) {
    float a = red[threadIdx.x] + red[threadIdx.x + 64] + red[threadIdx.x + 128] + red[threadIdx.x + 192];
    Dout[d.did * 1024 + b * 512 + co] = rsqrtf(a + 1e-8f);
  }
}

// ---------------- blur_up taps ----------------
__device__ inline void blur_taps(int o, int* r0, int* r1, float* w0, float* w1)
{
  if ((o & 1) == 0) { *r0 = (o >> 1) - 1; *w0 = 1.f; *r1 = (o >> 1); *w1 = 3.f; }
  else              { *r0 = (o - 1) >> 1; *w0 = 3.f; *r1 = ((o - 1) >> 1) + 1; *w1 = 1.f; }
}

// ---------------- prep_up: blur_up + style fold + bf16 cast (levels 2..4) ----------------
__global__ __launch_bounds__(256) void prep_up_kernel(
    const float* __restrict__ y, int Hc, int C,
    const float* __restrict__ s, unsigned short* __restrict__ out)
{
  int b = blockIdx.y;
  int W2 = Hc * 2;
  int pix = blockIdx.x;
  int oy = pix / W2, ox = pix - oy * W2;
  int ry0, ry1, rx0, rx1; float wy0, wy1, wx0, wx1;
  blur_taps(oy, &ry0, &ry1, &wy0, &wy1);
  blur_taps(ox, &rx0, &rx1, &wx0, &wx1);
  bool vy0 = (ry0 >= 0 && ry0 < Hc), vy1 = (ry1 >= 0 && ry1 < Hc);
  bool vx0 = (rx0 >= 0 && rx0 < Hc), vx1 = (rx1 >= 0 && rx1 < Hc);
  const float* base = y + (size_t)b * Hc * Hc * C;
  unsigned short* ob = out + (((size_t)b * W2 + oy) * W2 + ox) * C;
  const float* sv = s + b * 512;
  for (int c = threadIdx.x; c < C; c += 256) {
    float acc = 0.f;
    if (vy0) {
      const float* r = base + (size_t)(ry0 * Hc) * C;
      if (vx0) acc += wy0 * wx0 * r[(size_t)rx0 * C + c];
      if (vx1) acc += wy0 * wx1 * r[(size_t)rx1 * C + c];
    }
    if (vy1) {
      const float* r = base + (size_t)(ry1 * Hc) * C;
      if (vx0) acc += wy1 * wx0 * r[(size_t)rx0 * C + c];
      if (vx1) acc += wy1 * wx1 * r[(size_t)rx1 * C + c];
    }
    ob[c] = f2bf(acc * (1.f / 16.f) * sv[c]);
  }
}

// ---------------- MFMA implicit-GEMM 3x3 conv (levels 2..4) ----------------
// 8B-granular LDS layout: pixel stride 36 ushort (18 words), B row stride 292 (146 words).
// l15*18 mod 32 covers all 16 even residues -> 2 lanes/column per SIMD32 phase = free.
__global__ __launch_bounds__(256) void mfma_conv_kernel(
    const unsigned short* __restrict__ xp, int H, int WLOG, int Cin, int Cout,
    const unsigned short* __restrict__ wT,
    const float* __restrict__ bias, const float* __restrict__ dmod,
    float* __restrict__ outF, unsigned short* __restrict__ outBf,
    const float* __restrict__ sNext)
{
  extern __shared__ unsigned short sm[];
  const int W = 1 << WLOG;
  const int Rt = 128 >> WLOG;
  const int PR = Rt + 2, PC = W + 2;
  const int patchU = PR * PC * 36;
  unsigned short* Bw = sm + patchU;

  const int tid = threadIdx.x;
  const int wave = tid >> 6;
  const int lane = tid & 63;
  const int q = lane >> 4;
  const int l15 = lane & 15;

  const int HW = H << WLOG;
  const int m0 = blockIdx.x << 7;
  const int b = m0 / HW;
  const int y0 = (m0 - b * HW) >> WLOG;
  const int co0 = blockIdx.y << 6;
  const int Kp = Cin * 9;
  const unsigned short* xb = xp + (size_t)b * HW * Cin;

  const int pSlots = PR * PC * 4;
  int pLds[5], pSrc[5];
#pragma unroll
  for (int i = 0; i < 5; i++) {
    int sidx = tid + i * 256;
    pLds[i] = -1; pSrc[i] = -1;
    if (sidx < pSlots) {
      int pidx = sidx >> 2, part = sidx & 3;
      int pr = pidx / PC, pc = pidx - pr * PC;
      int gy = y0 + pr - 1, gx = pc - 1;
      pLds[i] = pidx * 36 + part * 8;
      if ((unsigned)gy < (unsigned)H && (unsigned)gx < (unsigned)W)
        pSrc[i] = ((gy << WLOG) + gx) * Cin + part * 8;
    }
  }
  int bLds[9], bSrc[9];
#pragma unroll
  for (int i = 0; i < 9; i++) {
    int sidx = tid + i * 256;
    int n = sidx / 36, c16 = sidx - n * 36;
    bLds[i] = n * 292 + c16 * 8;
    bSrc[i] = (co0 + n) * Kp + c16 * 8;
  }

  floatx4 zero = {0.f, 0.f, 0.f, 0.f};
  floatx4 acc[2][4];
#pragma unroll
  for (int mi = 0; mi < 2; mi++)
#pragma unroll
    for (int s = 0; s < 4; s++) acc[mi][s] = zero;

  const int mA0 = wave * 32 + l15;
  const int mA1 = mA0 + 16;
  const int aBase0 = ((mA0 >> WLOG) * PC + (mA0 & (W - 1))) * 36 + q * 8;
  const int aBase1 = ((mA1 >> WLOG) * PC + (mA1 & (W - 1))) * 36 + q * 8;
  const int bBase = l15 * 292 + q * 8;

  const int nGroups = Cin >> 5;
  for (int g = 0; g < nGroups; g++) {
    __syncthreads();
    {
      const int gci = g << 5;
#pragma unroll
      for (int i = 0; i < 5; i++) {
        if (pLds[i] >= 0) {
          uint4 v = {0u, 0u, 0u, 0u};
          if (pSrc[i] >= 0) v = *(const uint4*)(xb + pSrc[i] + gci);
          uint2 lo = {v.x, v.y}, hi = {v.z, v.w};
          *(uint2*)(sm + pLds[i]) = lo;
          *(uint2*)(sm + pLds[i] + 4) = hi;
        }
      }
      const int gw = g * 288;
#pragma unroll
      for (int i = 0; i < 9; i++) {
        uint4 v = *(const uint4*)(wT + bSrc[i] + gw);
        uint2 lo = {v.x, v.y}, hi = {v.z, v.w};
        *(uint2*)(Bw + bLds[i]) = lo;
        *(uint2*)(Bw + bLds[i] + 4) = hi;
      }
    }
    __syncthreads();
#pragma unroll
    for (int kt = 0; kt < 9; kt++) {
      const int ky = kt / 3, kx = kt - (kt / 3) * 3;
      const int ao = (ky * PC + kx) * 36;
      bf16x8 a0 = ld_frag8(sm + aBase0 + ao);
      bf16x8 a1 = ld_frag8(sm + aBase1 + ao);
      const int bo = bBase + kt * 32;
#pragma unroll
      for (int s = 0; s < 4; s++) {
        bf16x8 bb = ld_frag8(Bw + bo + s * (16 * 292));
        acc[0][s] = __builtin_amdgcn_mfma_f32_16x16x32_bf16(a0, bb, acc[0][s], 0, 0, 0);
        acc[1][s] = __builtin_amdgcn_mfma_f32_16x16x32_bf16(a1, bb, acc[1][s], 0, 0, 0);
      }
    }
  }

#pragma unroll
  for (int s = 0; s < 4; s++) {
    const int co = co0 + s * 16 + l15;
    const float dm = dmod[b * 512 + co];
    const float bv = bias[co];
    const float sn = sNext ? sNext[b * 512 + co] : 0.f;
#pragma unroll
    for (int mi = 0; mi < 2; mi++) {
#pragma unroll
      for (int r = 0; r < 4; r++) {
        const int mloc = wave * 32 + mi * 16 + q * 4 + r;
        const int py = y0 + (mloc >> WLOG);
        const int px = mloc & (W - 1);
        const size_t oidx = (((size_t)b * H + py) * W + px) * Cout + co;
        const float v = acc[mi][s][r] * dm + bv;
        if (outF) outF[oidx] = v;
        if (outBf) outBf[oidx] = f2bf(v * sn);
      }
    }
  }
}

// ---------------- split-K fp32 3x3 modulated conv (levels 0/1) ----------------
template<int PIX, int NCI4>
__global__ __launch_bounds__(256) void modconv_splitk_kernel(
    const float* __restrict__ x, size_t xBStride, int H, int W, int cinShift,
    int Cout,
    const float* __restrict__ w, const float* __restrict__ s,
    float* __restrict__ partial)
{
  constexpr int NCI = NCI4 * 4;
  constexpr int CLOG = (NCI == 16) ? 4 : (NCI == 32) ? 5 : 6;
  extern __shared__ float lds[];
  const int COLS = PIX + 2;
  const int tid = threadIdx.x;
  const int nthr = blockDim.x;
  const int b = blockIdx.y;
  const int z = blockIdx.z;
  const int ci0 = z << CLOG;
  const int wb = W / PIX;
  const int row = blockIdx.x / wb;
  const int x0 = (blockIdx.x % wb) * PIX;

  const float* xb = x + (size_t)b * xBStride;
  const float* sv = s + b * 512;

  const int tot = 3 * COLS << CLOG;
  for (int idx = tid; idx < tot; idx += nthr) {
    int cil = idx & (NCI - 1);
    int t = idx >> CLOG;
    int col = t % COLS;
    int ry = t / COLS;
    int gy = row + ry - 1;
    int gx = x0 + col - 1;
    float v = 0.f;
    if (gy >= 0 && gy < H && gx >= 0 && gx < W)
      v = xb[((size_t)(gy * W + gx) << cinShift) + ci0 + cil] * sv[ci0 + cil];
    lds[idx] = v;
  }
  __syncthreads();

  float acc0[PIX];
  float acc1[PIX];
#pragma unroll
  for (int p = 0; p < PIX; p++) { acc0[p] = 0.f; acc1[p] = 0.f; }
  const int co0 = tid;
  const int co1 = tid + nthr;
  const bool a0 = co0 < Cout;
  const bool a1 = co1 < Cout;
  const int d01 = nthr;

  const float4* ldsv = (const float4*)lds;
  constexpr int cin4Shift = CLOG - 2;

  for (int kt = 0; kt < 9; kt++) {
    int ky = kt / 3, kx = kt % 3;
    const float* wr = w + ((size_t)(kt << cinShift) + ci0) * Cout + co0;
#pragma unroll
    for (int c4 = 0; c4 < NCI4; c4++) {
      float wA0 = 0.f, wA1 = 0.f, wA2 = 0.f, wA3 = 0.f;
      float wB0 = 0.f, wB1 = 0.f, wB2 = 0.f, wB3 = 0.f;
      const float* wq = wr + (size_t)c4 * 4 * Cout;
      if (a0) { wA0 = wq[0]; }
      if (a1) { wB0 = wq[d01]; }
      if (a0) { wA1 = wq[Cout]; }
      if (a1) { wB1 = wq[Cout + d01]; }
      if (a0) { wA2 = wq[2 * Cout]; }
      if (a1) { wB2 = wq[2 * Cout + d01]; }
      if (a0) { wA3 = wq[3 * Cout]; }
      if (a1) { wB3 = wq[3 * Cout + d01]; }
#pragma unroll
      for (int p = 0; p < PIX; p++) {
        float4 v = ldsv[((ky * COLS + kx + p) << cin4Shift) + c4];
        acc0[p] += v.x * wA0; acc0[p] += v.y * wA1; acc0[p] += v.z * wA2; acc0[p] += v.w * wA3;
        acc1[p] += v.x * wB0; acc1[p] += v.y * wB1; acc1[p] += v.z * wB2; acc1[p] += v.w * wB3;
      }
    }
  }

  const int HW = H * W;
  float* pb = partial + ((size_t)(z * gridDim.y + b) * HW + row * W + x0) * Cout;
#pragma unroll
  for (int p = 0; p < PIX; p++) {
    if (a0) pb[(size_t)p * Cout + co0] = acc0[p];
    if (a1) pb[(size_t)p * Cout + co1] = acc1[p];
  }
}

// ---------------- u1 split-K with fused blur_up staging (y 4x4 -> 8x8 patch) ----------------
__global__ __launch_bounds__(128) void modconv_splitk_blur_kernel(
    const float* __restrict__ y, const float* __restrict__ w,
    const float* __restrict__ s, float* __restrict__ partial)
{
  // H=W=8, PIX=8, Cin=512 (chunk 16), Cout=128
  extern __shared__ float lds[];
  const int tid = threadIdx.x;
  const int b = blockIdx.y;
  const int z = blockIdx.z;
  const int ci0 = z << 4;
  const int row = blockIdx.x;

  const float* yb = y + (size_t)b * 16 * 512;
  const float* sv = s + b * 512;

  for (int idx = tid; idx < 480; idx += 128) {
    int cil = idx & 15;
    int t = idx >> 4;
    int col = t % 10;
    int ry = t / 10;
    int gy = row + ry - 1;
    int gx = col - 1;
    float v = 0.f;
    if ((unsigned)gy < 8u && (unsigned)gx < 8u) {
      int ry0, ry1, rx0, rx1; float wy0, wy1, wx0, wx1;
      blur_taps(gy, &ry0, &ry1, &wy0, &wy1);
      blur_taps(gx, &rx0, &rx1, &wx0, &wx1);
      bool vy0 = (ry0 >= 0 && ry0 < 4), vy1 = (ry1 >= 0 && ry1 < 4);
      bool vx0 = (rx0 >= 0 && rx0 < 4), vx1 = (rx1 >= 0 && rx1 < 4);
      int ci = ci0 + cil;
      float acc = 0.f;
      if (vy0 && vx0) acc += wy0 * wx0 * yb[((ry0 * 4 + rx0) << 9) + ci];
      if (vy0 && vx1) acc += wy0 * wx1 * yb[((ry0 * 4 + rx1) << 9) + ci];
      if (vy1 && vx0) acc += wy1 * wx0 * yb[((ry1 * 4 + rx0) << 9) + ci];
      if (vy1 && vx1) acc += wy1 * wx1 * yb[((ry1 * 4 + rx1) << 9) + ci];
      v = acc * (1.f / 16.f) * sv[ci];
    }
    lds[idx] = v;
  }
  __syncthreads();

  float acc0[8];
#pragma unroll
  for (int p = 0; p < 8; p++) acc0[p] = 0.f;
  const int co0 = tid;
  const float4* ldsv = (const float4*)lds;

  for (int kt = 0; kt < 9; kt++) {
    int ky = kt / 3, kx = kt % 3;
    const float* wr = w + ((size_t)(kt << 9) + ci0) * 128 + co0;
#pragma unroll
    for (int c4 = 0; c4 < 4; c4++) {
      const float* wq = wr + (size_t)c4 * 4 * 128;
      float wA0 = wq[0];
      float wA1 = wq[128];
      float wA2 = wq[256];
      float wA3 = wq[384];
#pragma unroll
      for (int p = 0; p < 8; p++) {
        float4 v = ldsv[((ky * 10 + kx + p) << 2) + c4];
        acc0[p] += v.x * wA0; acc0[p] += v.y * wA1; acc0[p] += v.z * wA2; acc0[p] += v.w * wA3;
      }
    }
  }

  float* pb = partial + ((size_t)(z * gridDim.y + b) * 64 + row * 8) * 128;
#pragma unroll
  for (int p = 0; p < 8; p++) pb[(size_t)p * 128 + co0] = acc0[p];
}

// ---------------- splitk epilogue (plain) ----------------
__global__ __launch_bounds__(256) void splitk_epi_kernel(
    const float* __restrict__ partial, int nz, int M, int Cout, int HW,
    const float* __restrict__ dmod, const float* __restrict__ bias,
    float* __restrict__ out)
{
  int idx = blockIdx.x * 256 + threadIdx.x;
  if (idx >= M * Cout) return;
  int m = idx / Cout;
  int co = idx - m * Cout;
  int b = m / HW;
  float acc = 0.f;
  for (int z = 0; z < nz; z++) acc += partial[(size_t)z * M * Cout + idx];
  out[idx] = acc * dmod[b * 512 + co] + bias[co];
}

// ---------------- fused splitk-epilogue + to_rgb (levels 0/1) ----------------
__global__ void epirgb_kernel(
    const float* __restrict__ P, int nz, int HW, int Cout, int W,
    const float* __restrict__ dmod, const float* __restrict__ bias,
    const float* __restrict__ noise, const float* __restrict__ ns, int doAct,
    const float* __restrict__ sR, const float* __restrict__ wR, const float* __restrict__ bR,
    const float* __restrict__ prev,
    float* __restrict__ yout, float* __restrict__ rgbout)
{
  __shared__ float red[24];
  int b = blockIdx.x / HW;
  int pix = blockIdx.x - b * HW;
  int co = threadIdx.x;
  int m = b * HW + pix;
  float acc = 0.f;
  for (int z = 0; z < nz; z++) acc += P[((size_t)(z * 2 + b) * HW + pix) * Cout + co];
  float v = acc * dmod[b * 512 + co] + bias[co];
  if (noise) v += ns[0] * noise[m];
  if (doAct) v = LEAKY(v);
  yout[(size_t)m * Cout + co] = v;
  float t = v * sR[b * 512 + co];
  float r0 = t * wR[co * 3 + 0];
  float r1 = t * wR[co * 3 + 1];
  float r2 = t * wR[co * 3 + 2];
  for (int off = 32; off > 0; off >>= 1) {
    r0 += __shfl_down(r0, off);
    r1 += __shfl_down(r1, off);
    r2 += __shfl_down(r2, off);
  }
  int wv = threadIdx.x >> 6, lane = threadIdx.x & 63;
  if (lane == 0) { red[wv * 3 + 0] = r0; red[wv * 3 + 1] = r1; red[wv * 3 + 2] = r2; }
  __syncthreads();
  if (threadIdx.x == 0) {
    int nw = blockDim.x >> 6;
    float s0 = bR[0], s1 = bR[1], s2 = bR[2];
    for (int w = 0; w < nw; w++) { s0 += red[w * 3]; s1 += red[w * 3 + 1]; s2 += red[w * 3 + 2]; }
    s0 = LEAKY(s0); s1 = LEAKY(s1); s2 = LEAKY(s2);
    if (prev) {
      int oy = pix / W, ox = pix - (pix / W) * W;
      int Hp = W >> 1;
      int ry0, ry1, rx0, rx1; float wy0, wy1, wx0, wx1;
      blur_taps(oy, &ry0, &ry1, &wy0, &wy1);
      blur_taps(ox, &rx0, &rx1, &wx0, &wx1);
      bool vy0 = (ry0 >= 0 && ry0 < Hp), vy1 = (ry1 >= 0 && ry1 < Hp);
      bool vx0 = (rx0 >= 0 && rx0 < Hp), vx1 = (rx1 >= 0 && rx1 < Hp);
      const float* base = prev + (size_t)b * Hp * Hp * 3;
      float a0 = 0.f, a1 = 0.f, a2 = 0.f;
      if (vy0 && vx0) { const float* qq = base + (size_t)(ry0 * Hp + rx0) * 3; float wg = wy0 * wx0; a0 += wg * qq[0]; a1 += wg * qq[1]; a2 += wg * qq[2]; }
      if (vy0 && vx1) { const float* qq = base + (size_t)(ry0 * Hp + rx1) * 3; float wg = wy0 * wx1; a0 += wg * qq[0]; a1 += wg * qq[1]; a2 += wg * qq[2]; }
      if (vy1 && vx0) { const float* qq = base + (size_t)(ry1 * Hp + rx0) * 3; float wg = wy1 * wx0; a0 += wg * qq[0]; a1 += wg * qq[1]; a2 += wg * qq[2]; }
      if (vy1 && vx1) { const float* qq = base + (size_t)(ry1 * Hp + rx1) * 3; float wg = wy1 * wx1; a0 += wg * qq[0]; a1 += wg * qq[1]; a2 += wg * qq[2]; }
      s0 += a0 * (1.f / 16.f); s1 += a1 * (1.f / 16.f); s2 += a2 * (1.f / 16.f);
    }
    rgbout[(size_t)m * 3 + 0] = s0;
    rgbout[(size_t)m * 3 + 1] = s1;
    rgbout[(size_t)m * 3 + 2] = s2;
  }
}

// ---------------- to_rgb (levels 2..4) ----------------
__global__ __launch_bounds__(64) void rgb_kernel(
    const float* __restrict__ y, int H, int W, int Cin,
    const float* __restrict__ w, const float* __restrict__ bias,
    const float* __restrict__ s, const float* __restrict__ prev,
    float* __restrict__ out)
{
  int b = blockIdx.y;
  int pix = blockIdx.x;
  int oy = pix / W, ox = pix % W;
  const float* xp = y + (((size_t)b * H + oy) * W + ox) * Cin;
  const float* sv = s + b * 512;
  float p0 = 0.f, p1 = 0.f, p2 = 0.f;
  for (int ci = threadIdx.x; ci < Cin; ci += 64) {
    float v = xp[ci] * sv[ci];
    p0 += v * w[ci * 3 + 0];
    p1 += v * w[ci * 3 + 1];
    p2 += v * w[ci * 3 + 2];
  }
  for (int off = 32; off > 0; off >>= 1) {
    p0 += __shfl_down(p0, off);
    p1 += __shfl_down(p1, off);
    p2 += __shfl_down(p2, off);
  }
  if (threadIdx.x == 0) {
    float r0 = p0 + bias[0], r1 = p1 + bias[1], r2 = p2 + bias[2];
    float sk0 = 0.f, sk1 = 0.f, sk2 = 0.f;
    if (prev) {
      int Hp = H >> 1, Wp = W >> 1;
      int ry0, ry1, rx0, rx1; float wy0, wy1, wx0, wx1;
      blur_taps(oy, &ry0, &ry1, &wy0, &wy1);
      blur_taps(ox, &rx0, &rx1, &wx0, &wx1);
      bool vy0 = (ry0 >= 0 && ry0 < Hp), vy1 = (ry1 >= 0 && ry1 < Hp);
      bool vx0 = (rx0 >= 0 && rx0 < Wp), vx1 = (rx1 >= 0 && rx1 < Wp);
      const float* base = prev + (size_t)b * Hp * Wp * 3;
      float a0 = 0.f, a1 = 0.f, a2 = 0.f;
      if (vy0 && vx0) { const float* qq = base + (size_t)(ry0 * Wp + rx0) * 3; float wg = wy0 * wx0; a0 += wg * qq[0]; a1 += wg * qq[1]; a2 += wg * qq[2]; }
      if (vy0 && vx1) { const float* qq = base + (size_t)(ry0 * Wp + rx1) * 3; float wg = wy0 * wx1; a0 += wg * qq[0]; a1 += wg * qq[1]; a2 += wg * qq[2]; }
      if (vy1 && vx0) { const float* qq = base + (size_t)(ry1 * Wp + rx0) * 3; float wg = wy1 * wx0; a0 += wg * qq[0]; a1 += wg * qq[1]; a2 += wg * qq[2]; }
      if (vy1 && vx1) { const float* qq = base + (size_t)(ry1 * Wp + rx1) * 3; float wg = wy1 * wx1; a0 += wg * qq[0]; a1 += wg * qq[1]; a2 += wg * qq[2]; }
      sk0 = a0 * (1.f / 16.f); sk1 = a1 * (1.f / 16.f); sk2 = a2 * (1.f / 16.f);
    }
    float* ob = out + (((size_t)b * H + oy) * W + ox) * 3;
    ob[0] = LEAKY(r0) + sk0;
    ob[1] = LEAKY(r1) + sk1;
    ob[2] = LEAKY(r2) + sk2;
  }
}

extern "C" void kernel_launch(void* const* d_in, const int* in_sizes, int n_in,
                              void* d_out, int out_size, void* d_ws, size_t ws_size,
                              hipStream_t stream)
{
  auto F = [&](int k) { return (const float*)d_in[k]; };
  const float* latents = F(0);
  const float* cnst = F(1);
  const float* w0 = F(2);  const float* b0 = F(3);  const float* sw0 = F(4);  const float* sb0 = F(5);
  const float* ns0 = F(6); const float* noise0 = F(7);
  const float* wr0 = F(8); const float* br0 = F(9); const float* swr0 = F(10); const float* sbr0 = F(11);
  const float *wu[4], *bu[4], *swu[4], *sbu[4];
  const float *wc[4], *bc[4], *swc[4], *sbc[4];
  const float *wr[4], *br_[4], *swr[4], *sbr[4];
  int k = 12;
  for (int l = 0; l < 4; l++) {
    wu[l] = F(k++); bu[l] = F(k++); swu[l] = F(k++); sbu[l] = F(k++);
    wc[l] = F(k++); bc[l] = F(k++); swc[l] = F(k++); sbc[l] = F(k++);
    wr[l] = F(k++); br_[l] = F(k++); swr[l] = F(k++); sbr[l] = F(k++);
  }

  // ---- workspace layout ----
  float* ws = (float*)d_ws;
  float* S = ws;                              // 14*1024
  float* D = S + 14 * 1024;                   // 9*1024
  float* W2 = D + 9 * 1024;                   // 1,359,872 floats
  float* bufA = W2 + 1359872;                 // 2*64*64*512
  float* bufB = bufA + 2 * 64 * 64 * 512;
  float* rgbA = bufB + 2 * 64 * 64 * 512;
  float* rgbB = rgbA + 2 * 64 * 64 * 3;
  float* P = rgbB + 2 * 64 * 64 * 3;          // split-K partials: 524288 floats
  unsigned short* u16 = (unsigned short*)(P + 524288);
  unsigned short* xprepA = u16;
  unsigned short* xprepB = xprepA + 2 * 64 * 64 * 512;
  unsigned short* wT[6];
  {
    unsigned short* p = xprepB + 2 * 64 * 64 * 512;
    int wsz[6] = {9 * 128 * 256, 9 * 256 * 256, 9 * 256 * 512, 9 * 512 * 512, 9 * 512 * 512, 9 * 512 * 512};
    for (int i = 0; i < 6; i++) { wT[i] = p; p += wsz[i]; }
  }

  const int B = 2;
  const int NFa[5] = {64, 128, 256, 512, 512};
  int cprev0[4] = {512, 128, 256, 512};
  int rowu[4] = {1, 6, 6, 6};

  const float* cw[9]  = {w0, wu[0], wc[0], wu[1], wc[1], wu[2], wc[2], wu[3], wc[3]};
  int cinL[9]  = {9, 9, 7, 7, 8, 8, 9, 9, 9};
  int coutL[9] = {9, 7, 7, 8, 8, 9, 9, 9, 9};
  int sidOf[9] = {0, 2, 3, 5, 6, 8, 9, 11, 12};
  int didOf[9] = {0, 1, 2, 3, 4, 5, 6, 7, 8};

  // ---- mega-prep: style + W2 + wprep in one dispatch ----
  int w2off[9];
  {
    StyleArgs SA;
    SA.d[0] = {sw0, sb0, 0, 512};
    SA.d[1] = {swr0, sbr0, 1, 512};
    for (int l = 0; l < 4; l++) {
      int c = NFa[l + 1];
      SA.d[2 + l * 3] = {swu[l], sbu[l], rowu[l], cprev0[l]};
      SA.d[3 + l * 3] = {swc[l], sbc[l], 5, c};
      SA.d[4 + l * 3] = {swr[l], sbr[l], 6, c};
    }
    W2Args WA2;
    int w2start = 0, off = 0;
    for (int i = 0; i < 9; i++) {
      w2off[i] = off;
      WA2.d[i] = {cw[i], cinL[i], coutL[i], w2start, off};
      int elems = 1 << (cinL[i] + coutL[i]);
      w2start += elems >> 2;
      off += elems;
    }
    WA2.total4 = w2start;
    WPArgs WPA;
    {
      const float* srcs[6] = {wu[1], wc[1], wu[2], wc[2], wu[3], wc[3]};
      int cins[6] = {128, 256, 256, 512, 512, 512};
      int couts[6] = {256, 256, 512, 512, 512, 512};
      int start = 0;
      for (int i = 0; i < 6; i++) {
        WPA.d[i] = {srcs[i], wT[i], cins[i], couts[i], start};
        start += couts[i] * cins[i] * 9 / 8;
      }
      WPA.total = start;
    }
    int styleBlocks = 56;
    int w2Blocks = (WA2.total4 + 255) / 256;
    int wpBlocks = (WPA.total + 255) / 256;
    prep_all_kernel<<<dim3(styleBlocks + w2Blocks + wpBlocks), 256, 0, stream>>>(
        latents, SA, WA2, WPA, S, W2, styleBlocks, w2Blocks);
  }

  // ---- demod2 ----
  {
    D2Args DA;
    int start = 0;
    for (int i = 0; i < 9; i++) {
      int cout = 1 << coutL[i];
      DA.d[i] = {w2off[i], sidOf[i], didOf[i], 1 << cinL[i], cout, start};
      start += B * (cout >> 6);
    }
    demod2_all_kernel<<<dim3(start), 256, 0, stream>>>(DA, W2, S, D);
  }

  // ---- conv0 (4x4, split-K z=32, chunk 16) + fused epi+rgb0 ----
  modconv_splitk_kernel<4, 4><<<dim3(4, B, 32), 256, (size_t)3 * 6 * 16 * 4, stream>>>(
      cnst, 0, 4, 4, 9, 512, w0, S, P);
  epirgb_kernel<<<dim3(B * 16), 512, 0, stream>>>(
      P, 32, 16, 512, 4, D, b0, noise0, ns0, 1,
      S + 1024, wr0, br0, nullptr, bufA, rgbA);

  // ---- level 1 (8x8): u1 with fused blur staging, epi, c1, fused epi+rgb1 ----
  modconv_splitk_blur_kernel<<<dim3(8, B, 32), 128, (size_t)480 * 4, stream>>>(
      bufA, wu[0], S + 2 * 1024, P);
  splitk_epi_kernel<<<dim3((128 * 128 + 255) / 256), 256, 0, stream>>>(
      P, 32, 128, 128, 64, D + 1 * 1024, bu[0], bufA);
  modconv_splitk_kernel<8, 4><<<dim3(8, B, 8), 128, (size_t)3 * 10 * 16 * 4, stream>>>(
      bufA, (size_t)64 * 128, 8, 8, 7, 128, wc[0], S + 3 * 1024, P);
  epirgb_kernel<<<dim3(B * 64), 128, 0, stream>>>(
      P, 8, 64, 128, 8, D + 2 * 1024, bc[0], nullptr, nullptr, 0,
      S + 4 * 1024, wr[0], br_[0], rgbA, bufB, rgbB);

  // ---- levels 2..4 (MFMA path) ----
  float* ybuf[4] = {bufB, bufA, bufB, bufA};
  float* rgbp = rgbB;
  const float* ysrc = bufB;
  int Hc = 8;
  for (int l = 1; l < 4; l++) {
    int c = NFa[l + 1];
    int cp = cprev0[l];
    int H2 = Hc * 2;
    int WLOG = (H2 == 16) ? 4 : (H2 == 32) ? 5 : 6;
    int wi = (l - 1) * 2;
    prep_up_kernel<<<dim3(H2 * H2, B), 256, 0, stream>>>(
        ysrc, Hc, cp, S + (2 + l * 3) * 1024, xprepA);
    {
      int PRu = (128 >> WLOG) + 2, PCu = H2 + 2;
      size_t lds = (size_t)(PRu * PCu * 36 + 64 * 292) * 2;
      mfma_conv_kernel<<<dim3((B * H2 * H2) / 128, c >> 6), 256, lds, stream>>>(
          xprepA, H2, WLOG, cp, c, wT[wi], bu[l], D + (1 + l * 2) * 1024,
          nullptr, xprepB, S + (3 + l * 3) * 1024);
    }
    float* yo = ybuf[l];
    {
      int PRu = (128 >> WLOG) + 2, PCu = H2 + 2;
      size_t lds = (size_t)(PRu * PCu * 36 + 64 * 292) * 2;
      mfma_conv_kernel<<<dim3((B * H2 * H2) / 128, c >> 6), 256, lds, stream>>>(
          xprepB, H2, WLOG, c, c, wT[wi + 1], bc[l], D + (2 + l * 2) * 1024,
          yo, nullptr, nullptr);
    }
    float* rout = (l == 3) ? (float*)d_out : ((rgbp == rgbA) ? rgbB : rgbA);
    rgb_kernel<<<dim3(H2 * H2, B), 64, 0, stream>>>(
        yo, H2, H2, c, wr[l], br_[l], S + (4 + l * 3) * 1024, rgbp, rout);
    rgbp = (rout == rgbA) ? rgbA : rgbB;
    ysrc = yo;
    Hc = H2;
  }
  (void)in_sizes; (void)n_in; (void)out_size; (void)ws_size;
}

// Round 8
// 553.492 us; speedup vs baseline: 1.1380x; 1.1380x over previous
//
#include <hip/hip_runtime.h>

#define LEAKY(v) ((v) > 0.f ? (v) : 0.01f * (v))

typedef __attribute__((ext_vector_type(8))) short bf16x8;
typedef __attribute__((ext_vector_type(4))) short bf16x4;
typedef __attribute__((ext_vector_type(4))) float floatx4;

__device__ inline unsigned short f2bf(float f) {
  unsigned u = __float_as_uint(f);
  unsigned r = u + 0x7FFFu + ((u >> 16) & 1u);
  return (unsigned short)(r >> 16);
}

__device__ inline bf16x8 ld_frag8(const unsigned short* p) {
  bf16x4 lo = *(const bf16x4*)p;
  bf16x4 hi = *(const bf16x4*)(p + 4);
  return __builtin_shufflevector(lo, hi, 0, 1, 2, 3, 4, 5, 6, 7);
}

// ---------------- mega-prep: style(14) + W2(9) + wprep-tiles(6 convs) in ONE dispatch ----------------
struct StyleDesc { const float* sw; const float* sb; int row; int cin; };
struct StyleArgs { StyleDesc d[14]; };
struct W2D { const float* w; int cinLog; int coutLog; int start; int w2off; };
struct W2Args { W2D d[9]; int total4; };
struct WTD { const float* src; unsigned short* dst; int cinLog; int coutLog; int start; };
struct WTArgs { WTD d[6]; int totalTiles; };

__device__ void style_body(int bid, const float* __restrict__ lat, const StyleArgs& A,
                           float* __restrict__ S)
{
  int chunk = bid & 1, b = (bid >> 1) & 1, sid = bid >> 2;
  StyleDesc d = A.d[sid];
  int ci = chunk * 256 + threadIdx.x;
  if (ci >= d.cin) return;
  const float* l = lat + (size_t)b * (10 * 512) + d.row * 512;
  float a0 = 0.f, a1 = 0.f, a2 = 0.f, a3 = 0.f, a4 = 0.f, a5 = 0.f, a6 = 0.f, a7 = 0.f;
  const float* wp = d.sw + ci;
  size_t st = d.cin;
  for (int k = 0; k < 512; k += 8) {
    a0 += l[k] * wp[0];
    a1 += l[k + 1] * wp[st];
    a2 += l[k + 2] * wp[2 * st];
    a3 += l[k + 3] * wp[3 * st];
    a4 += l[k + 4] * wp[4 * st];
    a5 += l[k + 5] * wp[5 * st];
    a6 += l[k + 6] * wp[6 * st];
    a7 += l[k + 7] * wp[7 * st];
    wp += 8 * st;
  }
  S[sid * 1024 + b * 512 + ci] = d.sb[ci] + ((a0 + a1) + (a2 + a3)) + ((a4 + a5) + (a6 + a7));
}

__device__ void w2_body(int idx, const W2Args& A, float* __restrict__ W2)
{
  if (idx >= A.total4) return;
  int c = 0;
  while (c < 8 && idx >= A.d[c + 1].start) c++;
  W2D d = A.d[c];
  int rel = idx - d.start;
  int co4Log = d.coutLog - 2;
  int ci = rel >> co4Log;
  int co = (rel & ((1 << co4Log) - 1)) << 2;
  size_t ktStride = (size_t)(1 << d.cinLog) << d.coutLog;
  const float* p = d.w + ((size_t)ci << d.coutLog) + co;
  float4 acc = {0.f, 0.f, 0.f, 0.f};
#pragma unroll
  for (int kt = 0; kt < 9; kt++) {
    float4 v = *(const float4*)(p + kt * ktStride);
    acc.x += v.x * v.x; acc.y += v.y * v.y; acc.z += v.z * v.z; acc.w += v.w * v.w;
  }
  *(float4*)(W2 + d.w2off + ((size_t)ci << d.coutLog) + co) = acc;
}

// tile transpose: source [kt][ci][co] fp32 (coalesced float4 reads) -> LDS [co][296] bf16
// -> dst [co][cig*288 + kt*32 + cisub] bf16 (coalesced b128 LDS reads, coalesced global writes)
__device__ void wprep_tile_body(int tile, const WTArgs& A, unsigned short* __restrict__ tl)
{
  int c = 0;
  while (c < 5 && tile >= A.d[c + 1].start) c++;
  WTD d = A.d[c];
  int rel = tile - d.start;
  int coTiles = 1 << (d.coutLog - 6);
  int cig = rel / coTiles;
  int co0 = (rel - cig * coTiles) << 6;
  int cin = 1 << d.cinLog, cout = 1 << d.coutLog;
  int tid = threadIdx.x;
  // load + transpose into LDS: 288 rows x 16 float4-cols
  for (int slot = tid; slot < 288 * 16; slot += 256) {
    int r = slot >> 4;            // kt*32 + cisub
    int co4 = slot & 15;
    int kt = r >> 5, cisub = r & 31;
    const float* sp = d.src + ((size_t)(kt * cin + (cig << 5) + cisub) << d.coutLog) + co0 + co4 * 4;
    float4 v = *(const float4*)sp;
    int cb = co4 * 4;
    tl[(cb + 0) * 296 + r] = f2bf(v.x);
    tl[(cb + 1) * 296 + r] = f2bf(v.y);
    tl[(cb + 2) * 296 + r] = f2bf(v.z);
    tl[(cb + 3) * 296 + r] = f2bf(v.w);
  }
  __syncthreads();
  int Kp = cin * 9;
  for (int slot = tid; slot < 64 * 36; slot += 256) {
    int co = slot / 36, c8 = slot - (slot / 36) * 36;
    bf16x4 lo = *(const bf16x4*)(tl + co * 296 + c8 * 8);
    bf16x4 hi = *(const bf16x4*)(tl + co * 296 + c8 * 8 + 4);
    unsigned short* op = d.dst + (size_t)(co0 + co) * Kp + cig * 288 + c8 * 8;
    *(bf16x4*)op = lo;
    *(bf16x4*)(op + 4) = hi;
  }
}

__global__ __launch_bounds__(256) void prep_all_kernel(
    const float* __restrict__ lat, StyleArgs SA, W2Args WA, WTArgs TA,
    float* __restrict__ S, float* __restrict__ W2, int styleBlocks, int w2Blocks)
{
  __shared__ unsigned short tl[64 * 296];
  int bid = blockIdx.x;
  if (bid < styleBlocks) { style_body(bid, lat, SA, S); return; }
  bid -= styleBlocks;
  if (bid < w2Blocks) { w2_body(bid * 256 + threadIdx.x, WA, W2); return; }
  bid -= w2Blocks;
  if (bid < TA.totalTiles) wprep_tile_body(bid, TA, tl);
}

// ---------------- demod2 ----------------
struct D2D { int w2off; int sid; int did; int cin; int cout; int start; };
struct D2Args { D2D d[9]; };

__global__ __launch_bounds__(256) void demod2_all_kernel(
    D2Args A, const float* __restrict__ W2, const float* __restrict__ S,
    float* __restrict__ Dout)
{
  __shared__ float red[256];
  int bid = blockIdx.x;
  int c = 0;
  while (c < 8 && bid >= A.d[c + 1].start) c++;
  D2D d = A.d[c];
  int rel = bid - d.start;
  int chunksPerB = d.cout >> 6;
  int b = rel / chunksPerB;
  int coc = rel - b * chunksPerB;
  int co = coc * 64 + (threadIdx.x & 63);
  int slice = threadIdx.x >> 6;
  const float* sv = S + d.sid * 1024 + b * 512;
  const float* wp = W2 + d.w2off + co;
  float a0 = 0.f, a1 = 0.f, a2 = 0.f, a3 = 0.f, a4 = 0.f, a5 = 0.f, a6 = 0.f, a7 = 0.f;
  for (int r = slice; r < d.cin; r += 32) {
    float s0 = sv[r];          a0 += s0 * s0 * wp[(size_t)r * d.cout];
    float s1 = sv[r + 4];      a1 += s1 * s1 * wp[(size_t)(r + 4) * d.cout];
    float s2 = sv[r + 8];      a2 += s2 * s2 * wp[(size_t)(r + 8) * d.cout];
    float s3 = sv[r + 12];     a3 += s3 * s3 * wp[(size_t)(r + 12) * d.cout];
    float s4 = sv[r + 16];     a4 += s4 * s4 * wp[(size_t)(r + 16) * d.cout];
    float s5 = sv[r + 20];     a5 += s5 * s5 * wp[(size_t)(r + 20) * d.cout];
    float s6 = sv[r + 24];     a6 += s6 * s6 * wp[(size_t)(r + 24) * d.cout];
    float s7 = sv[r + 28];     a7 += s7 * s7 * wp[(size_t)(r + 28) * d.cout];
  }
  red[threadIdx.x] = ((a0 + a1) + (a2 + a3)) + ((a4 + a5) + (a6 + a7));
  __syncthreads();
  if (threadIdx.x < 64) {
    float a = red[threadIdx.x] + red[threadIdx.x + 64] + red[threadIdx.x + 128] + red[threadIdx.x + 192];
    Dout[d.did * 1024 + b * 512 + co] = rsqrtf(a + 1e-8f);
  }
}

// ---------------- blur_up taps ----------------
__device__ inline void blur_taps(int o, int* r0, int* r1, float* w0, float* w1)
{
  if ((o & 1) == 0) { *r0 = (o >> 1) - 1; *w0 = 1.f; *r1 = (o >> 1); *w1 = 3.f; }
  else              { *r0 = (o - 1) >> 1; *w0 = 3.f; *r1 = ((o - 1) >> 1) + 1; *w1 = 1.f; }
}

// ---------------- prep_up: blur_up + style fold + bf16 cast (levels 2..4) ----------------
__global__ __launch_bounds__(256) void prep_up_kernel(
    const float* __restrict__ y, int Hc, int C,
    const float* __restrict__ s, unsigned short* __restrict__ out)
{
  int b = blockIdx.y;
  int W2 = Hc * 2;
  int pix = blockIdx.x;
  int oy = pix / W2, ox = pix - oy * W2;
  int ry0, ry1, rx0, rx1; float wy0, wy1, wx0, wx1;
  blur_taps(oy, &ry0, &ry1, &wy0, &wy1);
  blur_taps(ox, &rx0, &rx1, &wx0, &wx1);
  bool vy0 = (ry0 >= 0 && ry0 < Hc), vy1 = (ry1 >= 0 && ry1 < Hc);
  bool vx0 = (rx0 >= 0 && rx0 < Hc), vx1 = (rx1 >= 0 && rx1 < Hc);
  const float* base = y + (size_t)b * Hc * Hc * C;
  unsigned short* ob = out + (((size_t)b * W2 + oy) * W2 + ox) * C;
  const float* sv = s + b * 512;
  for (int c = threadIdx.x; c < C; c += 256) {
    float acc = 0.f;
    if (vy0) {
      const float* r = base + (size_t)(ry0 * Hc) * C;
      if (vx0) acc += wy0 * wx0 * r[(size_t)rx0 * C + c];
      if (vx1) acc += wy0 * wx1 * r[(size_t)rx1 * C + c];
    }
    if (vy1) {
      const float* r = base + (size_t)(ry1 * Hc) * C;
      if (vx0) acc += wy1 * wx0 * r[(size_t)rx0 * C + c];
      if (vx1) acc += wy1 * wx1 * r[(size_t)rx1 * C + c];
    }
    ob[c] = f2bf(acc * (1.f / 16.f) * sv[c]);
  }
}

// ---------------- MFMA implicit-GEMM 3x3 conv (levels 2..4) ----------------
// 8B-granular LDS layout (conflict-free) + register double-buffer prefetch of next ci-group.
__global__ __launch_bounds__(256) void mfma_conv_kernel(
    const unsigned short* __restrict__ xp, int H, int WLOG, int Cin, int Cout,
    const unsigned short* __restrict__ wT,
    const float* __restrict__ bias, const float* __restrict__ dmod,
    float* __restrict__ outF, unsigned short* __restrict__ outBf,
    const float* __restrict__ sNext)
{
  extern __shared__ unsigned short sm[];
  const int W = 1 << WLOG;
  const int Rt = 128 >> WLOG;
  const int PR = Rt + 2, PC = W + 2;
  const int patchU = PR * PC * 36;
  unsigned short* Bw = sm + patchU;

  const int tid = threadIdx.x;
  const int wave = tid >> 6;
  const int lane = tid & 63;
  const int q = lane >> 4;
  const int l15 = lane & 15;

  const int HW = H << WLOG;
  const int m0 = blockIdx.x << 7;
  const int b = m0 / HW;
  const int y0 = (m0 - b * HW) >> WLOG;
  const int co0 = blockIdx.y << 6;
  const int Kp = Cin * 9;
  const unsigned short* xb = xp + (size_t)b * HW * Cin;

  const int pSlots = PR * PC * 4;
  int pLds[5], pSrc[5];
#pragma unroll
  for (int i = 0; i < 5; i++) {
    int sidx = tid + i * 256;
    pLds[i] = -1; pSrc[i] = -1;
    if (sidx < pSlots) {
      int pidx = sidx >> 2, part = sidx & 3;
      int pr = pidx / PC, pc = pidx - pr * PC;
      int gy = y0 + pr - 1, gx = pc - 1;
      pLds[i] = pidx * 36 + part * 8;
      if ((unsigned)gy < (unsigned)H && (unsigned)gx < (unsigned)W)
        pSrc[i] = ((gy << WLOG) + gx) * Cin + part * 8;
    }
  }
  int bLds[9], bSrc[9];
#pragma unroll
  for (int i = 0; i < 9; i++) {
    int sidx = tid + i * 256;
    int n = sidx / 36, c16 = sidx - n * 36;
    bLds[i] = n * 292 + c16 * 8;
    bSrc[i] = (co0 + n) * Kp + c16 * 8;
  }

  floatx4 zero = {0.f, 0.f, 0.f, 0.f};
  floatx4 acc[2][4];
#pragma unroll
  for (int mi = 0; mi < 2; mi++)
#pragma unroll
    for (int s = 0; s < 4; s++) acc[mi][s] = zero;

  const int mA0 = wave * 32 + l15;
  const int mA1 = mA0 + 16;
  const int aBase0 = ((mA0 >> WLOG) * PC + (mA0 & (W - 1))) * 36 + q * 8;
  const int aBase1 = ((mA1 >> WLOG) * PC + (mA1 & (W - 1))) * 36 + q * 8;
  const int bBase = l15 * 292 + q * 8;

  const int nGroups = Cin >> 5;

  uint4 pv[5], bv[9];
  // prefetch group 0
  {
#pragma unroll
    for (int i = 0; i < 5; i++) {
      uint4 v = {0u, 0u, 0u, 0u};
      if (pLds[i] >= 0 && pSrc[i] >= 0) v = *(const uint4*)(xb + pSrc[i]);
      pv[i] = v;
    }
#pragma unroll
    for (int i = 0; i < 9; i++) bv[i] = *(const uint4*)(wT + bSrc[i]);
  }

  for (int g = 0; g < nGroups; g++) {
    __syncthreads();
#pragma unroll
    for (int i = 0; i < 5; i++) {
      if (pLds[i] >= 0) {
        uint2 lo = {pv[i].x, pv[i].y}, hi = {pv[i].z, pv[i].w};
        *(uint2*)(sm + pLds[i]) = lo;
        *(uint2*)(sm + pLds[i] + 4) = hi;
      }
    }
#pragma unroll
    for (int i = 0; i < 9; i++) {
      uint2 lo = {bv[i].x, bv[i].y}, hi = {bv[i].z, bv[i].w};
      *(uint2*)(Bw + bLds[i]) = lo;
      *(uint2*)(Bw + bLds[i] + 4) = hi;
    }
    __syncthreads();
    if (g + 1 < nGroups) {
      const int gci = (g + 1) << 5;
      const int gw = (g + 1) * 288;
#pragma unroll
      for (int i = 0; i < 5; i++) {
        uint4 v = {0u, 0u, 0u, 0u};
        if (pLds[i] >= 0 && pSrc[i] >= 0) v = *(const uint4*)(xb + pSrc[i] + gci);
        pv[i] = v;
      }
#pragma unroll
      for (int i = 0; i < 9; i++) bv[i] = *(const uint4*)(wT + bSrc[i] + gw);
    }
#pragma unroll
    for (int kt = 0; kt < 9; kt++) {
      const int ky = kt / 3, kx = kt - (kt / 3) * 3;
      const int ao = (ky * PC + kx) * 36;
      bf16x8 a0 = ld_frag8(sm + aBase0 + ao);
      bf16x8 a1 = ld_frag8(sm + aBase1 + ao);
      const int bo = bBase + kt * 32;
#pragma unroll
      for (int s = 0; s < 4; s++) {
        bf16x8 bb = ld_frag8(Bw + bo + s * (16 * 292));
        acc[0][s] = __builtin_amdgcn_mfma_f32_16x16x32_bf16(a0, bb, acc[0][s], 0, 0, 0);
        acc[1][s] = __builtin_amdgcn_mfma_f32_16x16x32_bf16(a1, bb, acc[1][s], 0, 0, 0);
      }
    }
  }

#pragma unroll
  for (int s = 0; s < 4; s++) {
    const int co = co0 + s * 16 + l15;
    const float dm = dmod[b * 512 + co];
    const float bv2 = bias[co];
    const float sn = sNext ? sNext[b * 512 + co] : 0.f;
#pragma unroll
    for (int mi = 0; mi < 2; mi++) {
#pragma unroll
      for (int r = 0; r < 4; r++) {
        const int mloc = wave * 32 + mi * 16 + q * 4 + r;
        const int py = y0 + (mloc >> WLOG);
        const int px = mloc & (W - 1);
        const size_t oidx = (((size_t)b * H + py) * W + px) * Cout + co;
        const float v = acc[mi][s][r] * dm + bv2;
        if (outF) outF[oidx] = v;
        if (outBf) outBf[oidx] = f2bf(v * sn);
      }
    }
  }
}

// ---------------- split-K fp32 3x3 modulated conv (levels 0/1) ----------------
template<int PIX, int NCI4>
__global__ __launch_bounds__(256) void modconv_splitk_kernel(
    const float* __restrict__ x, size_t xBStride, int H, int W, int cinShift,
    int Cout,
    const float* __restrict__ w, const float* __restrict__ s,
    float* __restrict__ partial)
{
  constexpr int NCI = NCI4 * 4;
  constexpr int CLOG = (NCI == 16) ? 4 : (NCI == 32) ? 5 : 6;
  extern __shared__ float lds[];
  const int COLS = PIX + 2;
  const int tid = threadIdx.x;
  const int nthr = blockDim.x;
  const int b = blockIdx.y;
  const int z = blockIdx.z;
  const int ci0 = z << CLOG;
  const int wb = W / PIX;
  const int row = blockIdx.x / wb;
  const int x0 = (blockIdx.x % wb) * PIX;

  const float* xb = x + (size_t)b * xBStride;
  const float* sv = s + b * 512;

  const int tot = 3 * COLS << CLOG;
  for (int idx = tid; idx < tot; idx += nthr) {
    int cil = idx & (NCI - 1);
    int t = idx >> CLOG;
    int col = t % COLS;
    int ry = t / COLS;
    int gy = row + ry - 1;
    int gx = x0 + col - 1;
    float v = 0.f;
    if (gy >= 0 && gy < H && gx >= 0 && gx < W)
      v = xb[((size_t)(gy * W + gx) << cinShift) + ci0 + cil] * sv[ci0 + cil];
    lds[idx] = v;
  }
  __syncthreads();

  float acc0[PIX];
  float acc1[PIX];
#pragma unroll
  for (int p = 0; p < PIX; p++) { acc0[p] = 0.f; acc1[p] = 0.f; }
  const int co0 = tid;
  const int co1 = tid + nthr;
  const bool a0 = co0 < Cout;
  const bool a1 = co1 < Cout;
  const int d01 = nthr;

  const float4* ldsv = (const float4*)lds;
  constexpr int cin4Shift = CLOG - 2;

  for (int kt = 0; kt < 9; kt++) {
    int ky = kt / 3, kx = kt % 3;
    const float* wr = w + ((size_t)(kt << cinShift) + ci0) * Cout + co0;
#pragma unroll
    for (int c4 = 0; c4 < NCI4; c4++) {
      float wA0 = 0.f, wA1 = 0.f, wA2 = 0.f, wA3 = 0.f;
      float wB0 = 0.f, wB1 = 0.f, wB2 = 0.f, wB3 = 0.f;
      const float* wq = wr + (size_t)c4 * 4 * Cout;
      if (a0) { wA0 = wq[0]; }
      if (a1) { wB0 = wq[d01]; }
      if (a0) { wA1 = wq[Cout]; }
      if (a1) { wB1 = wq[Cout + d01]; }
      if (a0) { wA2 = wq[2 * Cout]; }
      if (a1) { wB2 = wq[2 * Cout + d01]; }
      if (a0) { wA3 = wq[3 * Cout]; }
      if (a1) { wB3 = wq[3 * Cout + d01]; }
#pragma unroll
      for (int p = 0; p < PIX; p++) {
        float4 v = ldsv[((ky * COLS + kx + p) << cin4Shift) + c4];
        acc0[p] += v.x * wA0; acc0[p] += v.y * wA1; acc0[p] += v.z * wA2; acc0[p] += v.w * wA3;
        acc1[p] += v.x * wB0; acc1[p] += v.y * wB1; acc1[p] += v.z * wB2; acc1[p] += v.w * wB3;
      }
    }
  }

  const int HW = H * W;
  float* pb = partial + ((size_t)(z * gridDim.y + b) * HW + row * W + x0) * Cout;
#pragma unroll
  for (int p = 0; p < PIX; p++) {
    if (a0) pb[(size_t)p * Cout + co0] = acc0[p];
    if (a1) pb[(size_t)p * Cout + co1] = acc1[p];
  }
}

// ---------------- u1 split-K with fused blur_up staging ----------------
__global__ __launch_bounds__(128) void modconv_splitk_blur_kernel(
    const float* __restrict__ y, const float* __restrict__ w,
    const float* __restrict__ s, float* __restrict__ partial)
{
  extern __shared__ float lds[];
  const int tid = threadIdx.x;
  const int b = blockIdx.y;
  const int z = blockIdx.z;
  const int ci0 = z << 4;
  const int row = blockIdx.x;

  const float* yb = y + (size_t)b * 16 * 512;
  const float* sv = s + b * 512;

  for (int idx = tid; idx < 480; idx += 128) {
    int cil = idx & 15;
    int t = idx >> 4;
    int col = t % 10;
    int ry = t / 10;
    int gy = row + ry - 1;
    int gx = col - 1;
    float v = 0.f;
    if ((unsigned)gy < 8u && (unsigned)gx < 8u) {
      int ry0, ry1, rx0, rx1; float wy0, wy1, wx0, wx1;
      blur_taps(gy, &ry0, &ry1, &wy0, &wy1);
      blur_taps(gx, &rx0, &rx1, &wx0, &wx1);
      bool vy0 = (ry0 >= 0 && ry0 < 4), vy1 = (ry1 >= 0 && ry1 < 4);
      bool vx0 = (rx0 >= 0 && rx0 < 4), vx1 = (rx1 >= 0 && rx1 < 4);
      int ci = ci0 + cil;
      float acc = 0.f;
      if (vy0 && vx0) acc += wy0 * wx0 * yb[((ry0 * 4 + rx0) << 9) + ci];
      if (vy0 && vx1) acc += wy0 * wx1 * yb[((ry0 * 4 + rx1) << 9) + ci];
      if (vy1 && vx0) acc += wy1 * wx0 * yb[((ry1 * 4 + rx0) << 9) + ci];
      if (vy1 && vx1) acc += wy1 * wx1 * yb[((ry1 * 4 + rx1) << 9) + ci];
      v = acc * (1.f / 16.f) * sv[ci];
    }
    lds[idx] = v;
  }
  __syncthreads();

  float acc0[8];
#pragma unroll
  for (int p = 0; p < 8; p++) acc0[p] = 0.f;
  const int co0 = tid;
  const float4* ldsv = (const float4*)lds;

  for (int kt = 0; kt < 9; kt++) {
    int ky = kt / 3, kx = kt % 3;
    const float* wr = w + ((size_t)(kt << 9) + ci0) * 128 + co0;
#pragma unroll
    for (int c4 = 0; c4 < 4; c4++) {
      const float* wq = wr + (size_t)c4 * 4 * 128;
      float wA0 = wq[0];
      float wA1 = wq[128];
      float wA2 = wq[256];
      float wA3 = wq[384];
#pragma unroll
      for (int p = 0; p < 8; p++) {
        float4 v = ldsv[((ky * 10 + kx + p) << 2) + c4];
        acc0[p] += v.x * wA0; acc0[p] += v.y * wA1; acc0[p] += v.z * wA2; acc0[p] += v.w * wA3;
      }
    }
  }

  float* pb = partial + ((size_t)(z * gridDim.y + b) * 64 + row * 8) * 128;
#pragma unroll
  for (int p = 0; p < 8; p++) pb[(size_t)p * 128 + co0] = acc0[p];
}

// ---------------- splitk epilogue (plain) ----------------
__global__ __launch_bounds__(256) void splitk_epi_kernel(
    const float* __restrict__ partial, int nz, int M, int Cout, int HW,
    const float* __restrict__ dmod, const float* __restrict__ bias,
    float* __restrict__ out)
{
  int idx = blockIdx.x * 256 + threadIdx.x;
  if (idx >= M * Cout) return;
  int m = idx / Cout;
  int co = idx - m * Cout;
  int b = m / HW;
  float acc = 0.f;
  for (int z = 0; z < nz; z++) acc += partial[(size_t)z * M * Cout + idx];
  out[idx] = acc * dmod[b * 512 + co] + bias[co];
}

// ---------------- fused splitk-epilogue + to_rgb (levels 0/1) ----------------
__global__ void epirgb_kernel(
    const float* __restrict__ P, int nz, int HW, int Cout, int W,
    const float* __restrict__ dmod, const float* __restrict__ bias,
    const float* __restrict__ noise, const float* __restrict__ ns, int doAct,
    const float* __restrict__ sR, const float* __restrict__ wR, const float* __restrict__ bR,
    const float* __restrict__ prev,
    float* __restrict__ yout, float* __restrict__ rgbout)
{
  __shared__ float red[24];
  int b = blockIdx.x / HW;
  int pix = blockIdx.x - b * HW;
  int co = threadIdx.x;
  int m = b * HW + pix;
  float acc = 0.f;
  for (int z = 0; z < nz; z++) acc += P[((size_t)(z * 2 + b) * HW + pix) * Cout + co];
  float v = acc * dmod[b * 512 + co] + bias[co];
  if (noise) v += ns[0] * noise[m];
  if (doAct) v = LEAKY(v);
  yout[(size_t)m * Cout + co] = v;
  float t = v * sR[b * 512 + co];
  float r0 = t * wR[co * 3 + 0];
  float r1 = t * wR[co * 3 + 1];
  float r2 = t * wR[co * 3 + 2];
  for (int off = 32; off > 0; off >>= 1) {
    r0 += __shfl_down(r0, off);
    r1 += __shfl_down(r1, off);
    r2 += __shfl_down(r2, off);
  }
  int wv = threadIdx.x >> 6, lane = threadIdx.x & 63;
  if (lane == 0) { red[wv * 3 + 0] = r0; red[wv * 3 + 1] = r1; red[wv * 3 + 2] = r2; }
  __syncthreads();
  if (threadIdx.x == 0) {
    int nw = blockDim.x >> 6;
    float s0 = bR[0], s1 = bR[1], s2 = bR[2];
    for (int w = 0; w < nw; w++) { s0 += red[w * 3]; s1 += red[w * 3 + 1]; s2 += red[w * 3 + 2]; }
    s0 = LEAKY(s0); s1 = LEAKY(s1); s2 = LEAKY(s2);
    if (prev) {
      int oy = pix / W, ox = pix - (pix / W) * W;
      int Hp = W >> 1;
      int ry0, ry1, rx0, rx1; float wy0, wy1, wx0, wx1;
      blur_taps(oy, &ry0, &ry1, &wy0, &wy1);
      blur_taps(ox, &rx0, &rx1, &wx0, &wx1);
      bool vy0 = (ry0 >= 0 && ry0 < Hp), vy1 = (ry1 >= 0 && ry1 < Hp);
      bool vx0 = (rx0 >= 0 && rx0 < Hp), vx1 = (rx1 >= 0 && rx1 < Hp);
      const float* base = prev + (size_t)b * Hp * Hp * 3;
      float a0 = 0.f, a1 = 0.f, a2 = 0.f;
      if (vy0 && vx0) { const float* qq = base + (size_t)(ry0 * Hp + rx0) * 3; float wg = wy0 * wx0; a0 += wg * qq[0]; a1 += wg * qq[1]; a2 += wg * qq[2]; }
      if (vy0 && vx1) { const float* qq = base + (size_t)(ry0 * Hp + rx1) * 3; float wg = wy0 * wx1; a0 += wg * qq[0]; a1 += wg * qq[1]; a2 += wg * qq[2]; }
      if (vy1 && vx0) { const float* qq = base + (size_t)(ry1 * Hp + rx0) * 3; float wg = wy1 * wx0; a0 += wg * qq[0]; a1 += wg * qq[1]; a2 += wg * qq[2]; }
      if (vy1 && vx1) { const float* qq = base + (size_t)(ry1 * Hp + rx1) * 3; float wg = wy1 * wx1; a0 += wg * qq[0]; a1 += wg * qq[1]; a2 += wg * qq[2]; }
      s0 += a0 * (1.f / 16.f); s1 += a1 * (1.f / 16.f); s2 += a2 * (1.f / 16.f);
    }
    rgbout[(size_t)m * 3 + 0] = s0;
    rgbout[(size_t)m * 3 + 1] = s1;
    rgbout[(size_t)m * 3 + 2] = s2;
  }
}

// ---------------- to_rgb (levels 2..4) ----------------
__global__ __launch_bounds__(64) void rgb_kernel(
    const float* __restrict__ y, int H, int W, int Cin,
    const float* __restrict__ w, const float* __restrict__ bias,
    const float* __restrict__ s, const float* __restrict__ prev,
    float* __restrict__ out)
{
  int b = blockIdx.y;
  int pix = blockIdx.x;
  int oy = pix / W, ox = pix % W;
  const float* xp = y + (((size_t)b * H + oy) * W + ox) * Cin;
  const float* sv = s + b * 512;
  float p0 = 0.f, p1 = 0.f, p2 = 0.f;
  for (int ci = threadIdx.x; ci < Cin; ci += 64) {
    float v = xp[ci] * sv[ci];
    p0 += v * w[ci * 3 + 0];
    p1 += v * w[ci * 3 + 1];
    p2 += v * w[ci * 3 + 2];
  }
  for (int off = 32; off > 0; off >>= 1) {
    p0 += __shfl_down(p0, off);
    p1 += __shfl_down(p1, off);
    p2 += __shfl_down(p2, off);
  }
  if (threadIdx.x == 0) {
    float r0 = p0 + bias[0], r1 = p1 + bias[1], r2 = p2 + bias[2];
    float sk0 = 0.f, sk1 = 0.f, sk2 = 0.f;
    if (prev) {
      int Hp = H >> 1, Wp = W >> 1;
      int ry0, ry1, rx0, rx1; float wy0, wy1, wx0, wx1;
      blur_taps(oy, &ry0, &ry1, &wy0, &wy1);
      blur_taps(ox, &rx0, &rx1, &wx0, &wx1);
      bool vy0 = (ry0 >= 0 && ry0 < Hp), vy1 = (ry1 >= 0 && ry1 < Hp);
      bool vx0 = (rx0 >= 0 && rx0 < Wp), vx1 = (rx1 >= 0 && rx1 < Wp);
      const float* base = prev + (size_t)b * Hp * Wp * 3;
      float a0 = 0.f, a1 = 0.f, a2 = 0.f;
      if (vy0 && vx0) { const float* qq = base + (size_t)(ry0 * Wp + rx0) * 3; float wg = wy0 * wx0; a0 += wg * qq[0]; a1 += wg * qq[1]; a2 += wg * qq[2]; }
      if (vy0 && vx1) { const float* qq = base + (size_t)(ry0 * Wp + rx1) * 3; float wg = wy0 * wx1; a0 += wg * qq[0]; a1 += wg * qq[1]; a2 += wg * qq[2]; }
      if (vy1 && vx0) { const float* qq = base + (size_t)(ry1 * Wp + rx0) * 3; float wg = wy1 * wx0; a0 += wg * qq[0]; a1 += wg * qq[1]; a2 += wg * qq[2]; }
      if (vy1 && vx1) { const float* qq = base + (size_t)(ry1 * Wp + rx1) * 3; float wg = wy1 * wx1; a0 += wg * qq[0]; a1 += wg * qq[1]; a2 += wg * qq[2]; }
      sk0 = a0 * (1.f / 16.f); sk1 = a1 * (1.f / 16.f); sk2 = a2 * (1.f / 16.f);
    }
    float* ob = out + (((size_t)b * H + oy) * W + ox) * 3;
    ob[0] = LEAKY(r0) + sk0;
    ob[1] = LEAKY(r1) + sk1;
    ob[2] = LEAKY(r2) + sk2;
  }
}

extern "C" void kernel_launch(void* const* d_in, const int* in_sizes, int n_in,
                              void* d_out, int out_size, void* d_ws, size_t ws_size,
                              hipStream_t stream)
{
  auto F = [&](int k) { return (const float*)d_in[k]; };
  const float* latents = F(0);
  const float* cnst = F(1);
  const float* w0 = F(2);  const float* b0 = F(3);  const float* sw0 = F(4);  const float* sb0 = F(5);
  const float* ns0 = F(6); const float* noise0 = F(7);
  const float* wr0 = F(8); const float* br0 = F(9); const float* swr0 = F(10); const float* sbr0 = F(11);
  const float *wu[4], *bu[4], *swu[4], *sbu[4];
  const float *wc[4], *bc[4], *swc[4], *sbc[4];
  const float *wr[4], *br_[4], *swr[4], *sbr[4];
  int k = 12;
  for (int l = 0; l < 4; l++) {
    wu[l] = F(k++); bu[l] = F(k++); swu[l] = F(k++); sbu[l] = F(k++);
    wc[l] = F(k++); bc[l] = F(k++); swc[l] = F(k++); sbc[l] = F(k++);
    wr[l] = F(k++); br_[l] = F(k++); swr[l] = F(k++); sbr[l] = F(k++);
  }

  // ---- workspace layout ----
  float* ws = (float*)d_ws;
  float* S = ws;                              // 14*1024
  float* D = S + 14 * 1024;                   // 9*1024
  float* W2 = D + 9 * 1024;                   // 1,359,872 floats
  float* bufA = W2 + 1359872;                 // 2*64*64*512
  float* bufB = bufA + 2 * 64 * 64 * 512;
  float* rgbA = bufB + 2 * 64 * 64 * 512;
  float* rgbB = rgbA + 2 * 64 * 64 * 3;
  float* P = rgbB + 2 * 64 * 64 * 3;          // split-K partials: 524288 floats
  unsigned short* u16 = (unsigned short*)(P + 524288);
  unsigned short* xprepA = u16;
  unsigned short* xprepB = xprepA + 2 * 64 * 64 * 512;
  unsigned short* wT[6];
  {
    unsigned short* p = xprepB + 2 * 64 * 64 * 512;
    int wsz[6] = {9 * 128 * 256, 9 * 256 * 256, 9 * 256 * 512, 9 * 512 * 512, 9 * 512 * 512, 9 * 512 * 512};
    for (int i = 0; i < 6; i++) { wT[i] = p; p += wsz[i]; }
  }

  const int B = 2;
  const int NFa[5] = {64, 128, 256, 512, 512};
  int cprev0[4] = {512, 128, 256, 512};
  int rowu[4] = {1, 6, 6, 6};

  const float* cw[9]  = {w0, wu[0], wc[0], wu[1], wc[1], wu[2], wc[2], wu[3], wc[3]};
  int cinL[9]  = {9, 9, 7, 7, 8, 8, 9, 9, 9};
  int coutL[9] = {9, 7, 7, 8, 8, 9, 9, 9, 9};
  int sidOf[9] = {0, 2, 3, 5, 6, 8, 9, 11, 12};
  int didOf[9] = {0, 1, 2, 3, 4, 5, 6, 7, 8};

  // ---- mega-prep: style + W2 + wprep-tiles in one dispatch ----
  int w2off[9];
  {
    StyleArgs SA;
    SA.d[0] = {sw0, sb0, 0, 512};
    SA.d[1] = {swr0, sbr0, 1, 512};
    for (int l = 0; l < 4; l++) {
      int c = NFa[l + 1];
      SA.d[2 + l * 3] = {swu[l], sbu[l], rowu[l], cprev0[l]};
      SA.d[3 + l * 3] = {swc[l], sbc[l], 5, c};
      SA.d[4 + l * 3] = {swr[l], sbr[l], 6, c};
    }
    W2Args WA2;
    int w2start = 0, off = 0;
    for (int i = 0; i < 9; i++) {
      w2off[i] = off;
      WA2.d[i] = {cw[i], cinL[i], coutL[i], w2start, off};
      int elems = 1 << (cinL[i] + coutL[i]);
      w2start += elems >> 2;
      off += elems;
    }
    WA2.total4 = w2start;
    WTArgs TA;
    {
      const float* srcs[6] = {wu[1], wc[1], wu[2], wc[2], wu[3], wc[3]};
      int cinLg[6] = {7, 8, 8, 9, 9, 9};
      int coutLg[6] = {8, 8, 9, 9, 9, 9};
      int start = 0;
      for (int i = 0; i < 6; i++) {
        TA.d[i] = {srcs[i], wT[i], cinLg[i], coutLg[i], start};
        start += (1 << (cinLg[i] - 5)) * (1 << (coutLg[i] - 6));
      }
      TA.totalTiles = start;
    }
    int styleBlocks = 56;
    int w2Blocks = (WA2.total4 + 255) / 256;
    prep_all_kernel<<<dim3(styleBlocks + w2Blocks + TA.totalTiles), 256, 0, stream>>>(
        latents, SA, WA2, TA, S, W2, styleBlocks, w2Blocks);
  }

  // ---- demod2 ----
  {
    D2Args DA;
    int start = 0;
    for (int i = 0; i < 9; i++) {
      int cout = 1 << coutL[i];
      DA.d[i] = {w2off[i], sidOf[i], didOf[i], 1 << cinL[i], cout, start};
      start += B * (cout >> 6);
    }
    demod2_all_kernel<<<dim3(start), 256, 0, stream>>>(DA, W2, S, D);
  }

  // ---- conv0 (4x4, split-K z=32, chunk 16) + fused epi+rgb0 ----
  modconv_splitk_kernel<4, 4><<<dim3(4, B, 32), 256, (size_t)3 * 6 * 16 * 4, stream>>>(
      cnst, 0, 4, 4, 9, 512, w0, S, P);
  epirgb_kernel<<<dim3(B * 16), 512, 0, stream>>>(
      P, 32, 16, 512, 4, D, b0, noise0, ns0, 1,
      S + 1024, wr0, br0, nullptr, bufA, rgbA);

  // ---- level 1 (8x8): u1 with fused blur staging, epi, c1, fused epi+rgb1 ----
  modconv_splitk_blur_kernel<<<dim3(8, B, 32), 128, (size_t)480 * 4, stream>>>(
      bufA, wu[0], S + 2 * 1024, P);
  splitk_epi_kernel<<<dim3((128 * 128 + 255) / 256), 256, 0, stream>>>(
      P, 32, 128, 128, 64, D + 1 * 1024, bu[0], bufA);
  modconv_splitk_kernel<8, 4><<<dim3(8, B, 8), 128, (size_t)3 * 10 * 16 * 4, stream>>>(
      bufA, (size_t)64 * 128, 8, 8, 7, 128, wc[0], S + 3 * 1024, P);
  epirgb_kernel<<<dim3(B * 64), 128, 0, stream>>>(
      P, 8, 64, 128, 8, D + 2 * 1024, bc[0], nullptr, nullptr, 0,
      S + 4 * 1024, wr[0], br_[0], rgbA, bufB, rgbB);

  // ---- levels 2..4 (MFMA path) ----
  float* ybuf[4] = {bufB, bufA, bufB, bufA};
  float* rgbp = rgbB;
  const float* ysrc = bufB;
  int Hc = 8;
  for (int l = 1; l < 4; l++) {
    int c = NFa[l + 1];
    int cp = cprev0[l];
    int H2 = Hc * 2;
    int WLOG = (H2 == 16) ? 4 : (H2 == 32) ? 5 : 6;
    int wi = (l - 1) * 2;
    prep_up_kernel<<<dim3(H2 * H2, B), 256, 0, stream>>>(
        ysrc, Hc, cp, S + (2 + l * 3) * 1024, xprepA);
    {
      int PRu = (128 >> WLOG) + 2, PCu = H2 + 2;
      size_t lds = (size_t)(PRu * PCu * 36 + 64 * 292) * 2;
      mfma_conv_kernel<<<dim3((B * H2 * H2) / 128, c >> 6), 256, lds, stream>>>(
          xprepA, H2, WLOG, cp, c, wT[wi], bu[l], D + (1 + l * 2) * 1024,
          nullptr, xprepB, S + (3 + l * 3) * 1024);
    }
    float* yo = ybuf[l];
    {
      int PRu = (128 >> WLOG) + 2, PCu = H2 + 2;
      size_t lds = (size_t)(PRu * PCu * 36 + 64 * 292) * 2;
      mfma_conv_kernel<<<dim3((B * H2 * H2) / 128, c >> 6), 256, lds, stream>>>(
          xprepB, H2, WLOG, c, c, wT[wi + 1], bc[l], D + (2 + l * 2) * 1024,
          yo, nullptr, nullptr);
    }
    float* rout = (l == 3) ? (float*)d_out : ((rgbp == rgbA) ? rgbB : rgbA);
    rgb_kernel<<<dim3(H2 * H2, B), 64, 0, stream>>>(
        yo, H2, H2, c, wr[l], br_[l], S + (4 + l * 3) * 1024, rgbp, rout);
    rgbp = (rout == rgbA) ? rgbA : rgbB;
    ysrc = yo;
    Hc = H2;
  }
  (void)in_sizes; (void)n_in; (void)out_size; (void)ws_size;
}